// Round 12
// baseline (70.859 us; speedup 1.0000x reference)
//
#include <hip/hip_runtime.h>
#include <cstdint>

// Problem constants
#define BB 8
#define LL 2048
#define DD 768
#define SS 512
#define MAXW 32

constexpr int M = BB * SS;   // 4096 spans
constexpr int K = 2 * DD;    // 1536
constexpr int N = DD;        // 768

typedef __attribute__((ext_vector_type(8))) short short8;   // 8 bf16 = 4 VGPRs
typedef __attribute__((ext_vector_type(4))) float f32x4;

__device__ __forceinline__ unsigned short f2bf(float f) {
    union { float f; unsigned int u; } v; v.f = f;
    unsigned int r = v.u + 0x7fffu + ((v.u >> 16) & 1u);  // RNE
    return (unsigned short)(r >> 16);
}
__device__ __forceinline__ float bf2f(unsigned short u) {
    union { unsigned int u; float f; } v; v.u = ((unsigned int)u) << 16;
    return v.f;
}

// generic -> addrspace casts for global_load_lds
#define AS1(p) reinterpret_cast<const __attribute__((address_space(1))) void*>( \
                   reinterpret_cast<uintptr_t>(p))
#define AS3(p) reinterpret_cast<__attribute__((address_space(3))) void*>( \
                   reinterpret_cast<uintptr_t>(p))

constexpr int CAP = 64;      // max staged union rows (64 x 768 bf16 = 96 KB)

// ---------------------------------------------------------------------------
// Kernel 1: sorted UNION-ROW LDS-staged gather + W-transpose side blocks.
//  blocks [0,512): 512 thr = 8 waves = 8 rank-consecutive spans of batch
//    b = bid&7. Rank permutation computed in-block (LDS, deterministic).
//    Union window staged ONCE to LDS as bf16 (each row crosses the per-CU
//    load port once instead of ~4x); waves accumulate max/mean from LDS.
//    Fallback (union > CAP, block-uniform): r8-style direct f32 gather.
//  blocks [512, 512+1152): W_down (K x N f32) -> WT (N x K bf16).
// ---------------------------------------------------------------------------
__global__ __launch_bounds__(512) void span_wt_kernel(
    const float* __restrict__ repr,            // (B,L,D) f32
    const int*   __restrict__ spans,           // (B,S,2) int
    const float* __restrict__ W,               // (K,N) f32
    unsigned short* __restrict__ cat,          // (M, 2D) bf16
    unsigned short* __restrict__ WT)           // (N,K) bf16
{
    __shared__ unsigned short s_rows[CAP * DD];   // 96 KB staged rows
    __shared__ int s_start[512];
    __shared__ int s_ord[512];
    __shared__ int s_wst[8], s_wen[8];
    float (*tbuf)[33] = (float(*)[33])s_rows;     // alias for W path

    const int bid = blockIdx.x;
    const int tid = threadIdx.x;

    if (bid < 512) {
        const int b = bid & 7, g = bid >> 3;      // batch (XCD pin), rank group

        // int64-layout sniff (values < 2048 so high words zero under int64)
        const bool is64 = ((spans[1] | spans[3] | spans[5] | spans[7]) == 0);
        const int stride = is64 ? 4 : 2;
        const int eoff   = is64 ? 2 : 1;

        // ---- rank phase: start-order permutation (tie-break by index)
        s_start[tid] = spans[(size_t)stride * ((b << 9) + tid)];
        __syncthreads();
        {
            const int sti = s_start[tid];
            int r = 0;
            #pragma unroll 8
            for (int j = 0; j < 512; ++j) {
                const int stj = s_start[j];       // LDS broadcast
                r += (int)((stj < sti) | ((stj == sti) & (j < tid)));
            }
            s_ord[r] = tid;                       // permutation: no conflicts
        }
        __syncthreads();

        const int wave = tid >> 6, lane = tid & 63;
        const int span = (b << 9) | s_ord[g * 8 + wave];   // wave-uniform
        const int st = spans[(size_t)stride * span];
        const int en = spans[(size_t)stride * span + eoff];
        const int cnt = en - st + 1;              // 1..32

        // ---- block union window
        if (tid < 8) {
            const int sp = (b << 9) | s_ord[g * 8 + tid];
            s_wst[tid] = spans[(size_t)stride * sp];
            s_wen[tid] = spans[(size_t)stride * sp + eoff];
        }
        __syncthreads();
        int U_lo = s_wst[0], U_hi = s_wen[0];
        #pragma unroll
        for (int i = 1; i < 8; ++i) {
            U_lo = min(U_lo, s_wst[i]);
            U_hi = max(U_hi, s_wen[i]);
        }
        const int rows = U_hi - U_lo + 1;         // block-uniform

        const float4* base = (const float4*)repr + (size_t)b * LL * (DD / 4);

        float4 mx[3], sm[3];
        #pragma unroll
        for (int c = 0; c < 3; ++c) {
            mx[c] = make_float4(-3.0e38f, -3.0e38f, -3.0e38f, -3.0e38f);
            sm[c] = make_float4(0.f, 0.f, 0.f, 0.f);
        }

        if (rows <= CAP) {
            // ---- stage union rows once (wave w takes rows w, w+8, ...)
            for (int r = wave; r < rows; r += 8) {
                const float4* rp = base + (size_t)(U_lo + r) * (DD / 4);
                #pragma unroll
                for (int c = 0; c < 3; ++c) {
                    const float4 v = rp[lane + 64 * c];
                    ushort4 o;
                    o.x = f2bf(v.x); o.y = f2bf(v.y);
                    o.z = f2bf(v.z); o.w = f2bf(v.w);
                    *(ushort4*)&s_rows[r * DD + (lane + 64 * c) * 4] = o;
                }
            }
            __syncthreads();

            // ---- accumulate own window from LDS
            #pragma unroll 2
            for (int w = 0; w < cnt; ++w) {
                const int r = st - U_lo + w;
                #pragma unroll
                for (int c = 0; c < 3; ++c) {
                    const ushort4 u =
                        *(const ushort4*)&s_rows[r * DD + (lane + 64 * c) * 4];
                    const float x0 = bf2f(u.x), x1 = bf2f(u.y);
                    const float x2 = bf2f(u.z), x3 = bf2f(u.w);
                    mx[c].x = fmaxf(mx[c].x, x0); mx[c].y = fmaxf(mx[c].y, x1);
                    mx[c].z = fmaxf(mx[c].z, x2); mx[c].w = fmaxf(mx[c].w, x3);
                    sm[c].x += x0; sm[c].y += x1; sm[c].z += x2; sm[c].w += x3;
                }
            }
        } else {
            // ---- fallback: direct f32 gather (r8-proven path), x2 unroll
            int w = 0;
            if (cnt & 1) {
                const float4* rp = base + (size_t)en * (DD / 4) + lane;
                const float4 a0 = rp[0], a1 = rp[64], a2 = rp[128];
                #define ACC(c, v)                                              \
                    mx[c].x = fmaxf(mx[c].x, (v).x); mx[c].y = fmaxf(mx[c].y, (v).y); \
                    mx[c].z = fmaxf(mx[c].z, (v).z); mx[c].w = fmaxf(mx[c].w, (v).w); \
                    sm[c].x += (v).x; sm[c].y += (v).y; sm[c].z += (v).z; sm[c].w += (v).w;
                ACC(0, a0); ACC(1, a1); ACC(2, a2);
                w = 1;
            }
            for (; w < cnt; w += 2) {
                const float4* r0 = base + (size_t)(en - w) * (DD / 4) + lane;
                const float4* r1 = r0 - (DD / 4);
                const float4 a0 = r0[0], a1 = r0[64], a2 = r0[128];
                const float4 b0 = r1[0], b1 = r1[64], b2 = r1[128];
                ACC(0, a0); ACC(1, a1); ACC(2, a2);
                ACC(0, b0); ACC(1, b1); ACC(2, b2);
            }
            #undef ACC
        }

        // ---- write cat row (max | mean), bf16
        const float inv = 1.0f / (float)cnt;
        unsigned short* crow = cat + (size_t)span * K;
        #pragma unroll
        for (int c = 0; c < 3; ++c) {
            const int d4 = lane + 64 * c;          // float4 index within row
            ushort4 omax, omean;
            omax.x  = f2bf(mx[c].x);       omax.y  = f2bf(mx[c].y);
            omax.z  = f2bf(mx[c].z);       omax.w  = f2bf(mx[c].w);
            omean.x = f2bf(sm[c].x * inv); omean.y = f2bf(sm[c].y * inv);
            omean.z = f2bf(sm[c].z * inv); omean.w = f2bf(sm[c].w * inv);
            *(ushort4*)(crow + d4 * 4)      = omax;
            *(ushort4*)(crow + DD + d4 * 4) = omean;
        }
    } else {
        // ---- W transpose+cast: 24 x 48 tiles of 32x32, 512 threads (32,16)
        const int tt = bid - 512;
        const int n0 = (tt % 24) * 32, k0 = (tt / 24) * 32;
        const int tx = tid & 31, ty = tid >> 5;      // (32, 16)
        #pragma unroll
        for (int j = 0; j < 2; ++j)
            tbuf[ty + 16 * j][tx] = W[(size_t)(k0 + ty + 16 * j) * N + n0 + tx];
        __syncthreads();
        #pragma unroll
        for (int j = 0; j < 2; ++j)
            WT[(size_t)(n0 + ty + 16 * j) * K + k0 + tx] = f2bf(tbuf[tx][ty + 16 * j]);
    }
}

// ---------------------------------------------------------------------------
// Kernel 2: out = cat(bf16) @ WT(bf16)^T + bias, MFMA 16x16x32.
// BM=BN=BK=64; 256 threads = 4 waves (2x2); wave tile 32x32.
// Double-buffered prefetch-before-compute; grid 768 = 3 blocks/CU.
// XCD swizzle: 96 tiles/XCD. (UNCHANGED — measured ~12-14us.)
// ---------------------------------------------------------------------------
constexpr int BM = 64, BN = 64, BK = 64;

__global__ __launch_bounds__(256) void gemm_bias_kernel(
    const unsigned short* __restrict__ A,    // (M, K)  bf16
    const unsigned short* __restrict__ WT,   // (N, K)  bf16
    const float* __restrict__ bias,          // (N)     f32
    float*       __restrict__ C)             // (M, N)  f32
{
    __shared__ unsigned short Asm[2][BM * BK];  // 2 x 8 KB, swizzled chunks
    __shared__ unsigned short Bsm[2][BN * BK];  // 2 x 8 KB

    const int tid = threadIdx.x;
    const int tile = (blockIdx.x & 7) * 96 + (blockIdx.x >> 3);
    const int mt = tile / 12, nt = tile % 12;
    const int m0 = mt * BM, n0 = nt * BN;

    const int lane = tid & 63;
    const int wid  = tid >> 6;
    const int wm = wid >> 1, wn = wid & 1;   // 2x2 wave grid, wave tile 32x32
    const int lnib = lane & 15, hi = lane >> 4;

    f32x4 acc[2][2] = {};

    auto stage = [&](int k0, int buf) {
        #pragma unroll
        for (int it = 0; it < 2; ++it) {
            const int s   = it * 256 + tid;
            const int row = s >> 3, c8 = s & 7;
            const unsigned short* g =
                A + (size_t)(m0 + row) * K + k0 + ((c8 ^ (row & 7)) << 3);
            __builtin_amdgcn_global_load_lds(AS1(g), AS3(&Asm[buf][s << 3]), 16, 0, 0);
        }
        #pragma unroll
        for (int it = 0; it < 2; ++it) {
            const int s   = it * 256 + tid;
            const int row = s >> 3, c8 = s & 7;
            const unsigned short* g =
                WT + (size_t)(n0 + row) * K + k0 + ((c8 ^ (row & 7)) << 3);
            __builtin_amdgcn_global_load_lds(AS1(g), AS3(&Bsm[buf][s << 3]), 16, 0, 0);
        }
    };

    auto compute = [&](int buf) {
        #pragma unroll
        for (int kk = 0; kk < 2; ++kk) {
            short8 af[2], bf[2];
            const int cc = kk * 4 + hi;
            #pragma unroll
            for (int mf = 0; mf < 2; ++mf) {
                const int r = wm * 32 + mf * 16 + lnib;
                af[mf] = *(const short8*)&Asm[buf][(r * 8 + (cc ^ (r & 7))) << 3];
            }
            #pragma unroll
            for (int nf = 0; nf < 2; ++nf) {
                const int r = wn * 32 + nf * 16 + lnib;
                bf[nf] = *(const short8*)&Bsm[buf][(r * 8 + (cc ^ (r & 7))) << 3];
            }
            #pragma unroll
            for (int mf = 0; mf < 2; ++mf)
                #pragma unroll
                for (int nf = 0; nf < 2; ++nf)
                    acc[mf][nf] = __builtin_amdgcn_mfma_f32_16x16x32_bf16(
                        af[mf], bf[nf], acc[mf][nf], 0, 0, 0);
        }
    };

    constexpr int NT = K / BK;   // 24 K-steps

    stage(0, 0);
    __syncthreads();             // vmcnt(0) drain: buf0 ready

    int cur = 0;
    #pragma unroll 1
    for (int t = 0; t < NT - 1; ++t) {
        stage((t + 1) * BK, cur ^ 1);  // issue next tile's loads first
        compute(cur);                   // MFMA on current while loads fly
        __syncthreads();                // next buf ready; cur free to reuse
        cur ^= 1;
    }
    compute(cur);

    // Epilogue: bias + store. C/D: col = lane&15, row = hi*4 + reg.
    #pragma unroll
    for (int nf = 0; nf < 2; ++nf) {
        const int col = n0 + wn * 32 + nf * 16 + lnib;
        const float bv = bias[col];
        #pragma unroll
        for (int mf = 0; mf < 2; ++mf) {
            const int rbase = m0 + wm * 32 + mf * 16 + hi * 4;
            #pragma unroll
            for (int r = 0; r < 4; ++r)
                C[(size_t)(rbase + r) * N + col] = acc[mf][nf][r] + bv;
        }
    }
}

// ---------------------------------------------------------------------------
extern "C" void kernel_launch(void* const* d_in, const int* in_sizes, int n_in,
                              void* d_out, int out_size, void* d_ws, size_t ws_size,
                              hipStream_t stream)
{
    const float* repr  = (const float*)d_in[0];  // (B,L,D) f32
    const int*   spans = (const int*)  d_in[1];  // (B,S,2)
    const float* Wd    = (const float*)d_in[2];  // (2D,D) f32
    const float* bias  = (const float*)d_in[3];  // (D)    f32
    float* out = (float*)d_out;                  // (M, N) f32

    unsigned short* catb = (unsigned short*)d_ws;             // M*K = 12.6 MB
    unsigned short* WT   = catb + (size_t)M * K;              // N*K =  2.4 MB

    span_wt_kernel<<<512 + 1152, 512, 0, stream>>>(repr, spans, Wd, catb, WT);
    gemm_bias_kernel<<<768, 256, 0, stream>>>(catb, WT, bias, out);
}

// Round 13
// 41.221 us; speedup vs baseline: 1.7190x; 1.7190x over previous
//
#include <hip/hip_runtime.h>
#include <cstdint>

// Problem constants
#define BB 8
#define LL 2048
#define DD 768
#define SS 512
#define MAXW 32

constexpr int M = BB * SS;   // 4096 spans
constexpr int K = 2 * DD;    // 1536
constexpr int N = DD;        // 768

typedef __attribute__((ext_vector_type(8))) short short8;   // 8 bf16 = 4 VGPRs
typedef __attribute__((ext_vector_type(4))) float f32x4;

__device__ __forceinline__ unsigned short f2bf(float f) {
    union { float f; unsigned int u; } v; v.f = f;
    unsigned int r = v.u + 0x7fffu + ((v.u >> 16) & 1u);  // RNE
    return (unsigned short)(r >> 16);
}

// generic -> addrspace casts for global_load_lds
#define AS1(p) reinterpret_cast<const __attribute__((address_space(1))) void*>( \
                   reinterpret_cast<uintptr_t>(p))
#define AS3(p) reinterpret_cast<__attribute__((address_space(3))) void*>( \
                   reinterpret_cast<uintptr_t>(p))

// ---------------------------------------------------------------------------
// Kernel 1 (fused span + W-transpose) — r7/r11 structure, measured 41.3/41.6us.
//  blocks [0, 4096): per-span masked max+mean reading repr f32 directly.
//    192 threads, float4/lane, row loop unrolled x2 with dual accumulators.
//    Runs at the measured per-CU load-port ceiling (~8.2 TB/s logical;
//    byte-proportional across precision and cache residency — r6/r8/r10).
//    All staging/sorting/fusion alternatives measured slower (r9/r10/r12).
//  blocks [4096, 4096+1152): W_down (K x N f32) -> WT (N x K bf16).
// ---------------------------------------------------------------------------
__global__ __launch_bounds__(192) void span_wt_kernel(
    const float* __restrict__ repr,            // (B,L,D) f32
    const int*   __restrict__ spans,           // (B,S,2) int
    const float* __restrict__ W,               // (K,N) f32
    unsigned short* __restrict__ cat,          // (M, 2D) bf16
    unsigned short* __restrict__ WT)           // (N,K) bf16
{
    __shared__ float tbuf[32][33];
    const int bid = blockIdx.x;
    const int tid = threadIdx.x;

    if (bid < 4096) {
        const int b = bid & 7, s = bid >> 3;
        const int span = (b << 9) | s;
        const int t = tid;                     // 0..191, 4 dims (float4) each

        // int64-layout sniff (values < 2048 so high words zero under int64)
        const bool is64 = ((spans[1] | spans[3] | spans[5] | spans[7]) == 0);
        int st, en;
        if (is64) { st = spans[4 * span];     en = spans[4 * span + 2]; }
        else      { st = spans[2 * span];     en = spans[2 * span + 1]; }
        const int cnt = en - st + 1;           // 1..32, block-uniform

        const float4* base = (const float4*)repr + (size_t)b * LL * (DD / 4);

        float4 mx0 = make_float4(-3.0e38f, -3.0e38f, -3.0e38f, -3.0e38f);
        float4 mx1 = mx0;
        float4 sm0 = make_float4(0.f, 0.f, 0.f, 0.f);
        float4 sm1 = sm0;

        int w = 0;
        if (cnt & 1) {                          // odd count: peel one row
            const float4 v = base[(size_t)en * (DD / 4) + t];
            mx0.x = fmaxf(mx0.x, v.x);  mx0.y = fmaxf(mx0.y, v.y);
            mx0.z = fmaxf(mx0.z, v.z);  mx0.w = fmaxf(mx0.w, v.w);
            sm0.x += v.x;  sm0.y += v.y;  sm0.z += v.z;  sm0.w += v.w;
            w = 1;
        }
        for (; w < cnt; w += 2) {               // two independent load chains
            const float4 v0 = base[(size_t)(en - w)     * (DD / 4) + t];
            const float4 v1 = base[(size_t)(en - w - 1) * (DD / 4) + t];
            mx0.x = fmaxf(mx0.x, v0.x);  mx0.y = fmaxf(mx0.y, v0.y);
            mx0.z = fmaxf(mx0.z, v0.z);  mx0.w = fmaxf(mx0.w, v0.w);
            sm0.x += v0.x;  sm0.y += v0.y;  sm0.z += v0.z;  sm0.w += v0.w;
            mx1.x = fmaxf(mx1.x, v1.x);  mx1.y = fmaxf(mx1.y, v1.y);
            mx1.z = fmaxf(mx1.z, v1.z);  mx1.w = fmaxf(mx1.w, v1.w);
            sm1.x += v1.x;  sm1.y += v1.y;  sm1.z += v1.z;  sm1.w += v1.w;
        }
        const float4 mx = make_float4(fmaxf(mx0.x, mx1.x), fmaxf(mx0.y, mx1.y),
                                      fmaxf(mx0.z, mx1.z), fmaxf(mx0.w, mx1.w));
        const float4 sm = make_float4(sm0.x + sm1.x, sm0.y + sm1.y,
                                      sm0.z + sm1.z, sm0.w + sm1.w);

        const float inv = 1.0f / (float)cnt;
        unsigned short* crow = cat + (size_t)span * K;
        ushort4 omax, omean;
        omax.x  = f2bf(mx.x);       omax.y  = f2bf(mx.y);
        omax.z  = f2bf(mx.z);       omax.w  = f2bf(mx.w);
        omean.x = f2bf(sm.x * inv); omean.y = f2bf(sm.y * inv);
        omean.z = f2bf(sm.z * inv); omean.w = f2bf(sm.w * inv);
        *(ushort4*)(crow + t * 4)      = omax;
        *(ushort4*)(crow + DD + t * 4) = omean;
    } else {
        // ---- W transpose+cast: 24 x 48 tiles of 32x32, 192 threads
        const int tt = bid - 4096;
        const int n0 = (tt % 24) * 32, k0 = (tt / 24) * 32;
        const int tx = tid & 31, ty = tid >> 5;      // (32, 6)
        #pragma unroll
        for (int j = 0; j < 6; ++j) {
            const int row = ty + 6 * j;              // 0..35
            if (row < 32)
                tbuf[row][tx] = W[(size_t)(k0 + row) * N + n0 + tx];
        }
        __syncthreads();
        #pragma unroll
        for (int j = 0; j < 6; ++j) {
            const int row = ty + 6 * j;
            if (row < 32)
                WT[(size_t)(n0 + row) * K + k0 + tx] = f2bf(tbuf[tx][row]);
        }
    }
}

// ---------------------------------------------------------------------------
// Kernel 2: out = cat(bf16) @ WT(bf16)^T + bias, MFMA 16x16x32.
// BM=BN=BK=64; 256 threads = 4 waves (2x2); wave tile 32x32.
// Double-buffered prefetch-before-compute; grid 768 = 3 blocks/CU.
// XCD swizzle: 96 tiles/XCD -> A panel 1.57 MB + WT 2.4 MB ~ L2-resident.
// ---------------------------------------------------------------------------
constexpr int BM = 64, BN = 64, BK = 64;

__global__ __launch_bounds__(256) void gemm_bias_kernel(
    const unsigned short* __restrict__ A,    // (M, K)  bf16
    const unsigned short* __restrict__ WT,   // (N, K)  bf16
    const float* __restrict__ bias,          // (N)     f32
    float*       __restrict__ C)             // (M, N)  f32
{
    __shared__ unsigned short Asm[2][BM * BK];  // 2 x 8 KB, swizzled chunks
    __shared__ unsigned short Bsm[2][BN * BK];  // 2 x 8 KB

    const int tid = threadIdx.x;
    const int tile = (blockIdx.x & 7) * 96 + (blockIdx.x >> 3);
    const int mt = tile / 12, nt = tile % 12;
    const int m0 = mt * BM, n0 = nt * BN;

    const int lane = tid & 63;
    const int wid  = tid >> 6;
    const int wm = wid >> 1, wn = wid & 1;   // 2x2 wave grid, wave tile 32x32
    const int lnib = lane & 15, hi = lane >> 4;

    f32x4 acc[2][2] = {};

    auto stage = [&](int k0, int buf) {
        #pragma unroll
        for (int it = 0; it < 2; ++it) {
            const int s   = it * 256 + tid;
            const int row = s >> 3, c8 = s & 7;
            const unsigned short* g =
                A + (size_t)(m0 + row) * K + k0 + ((c8 ^ (row & 7)) << 3);
            __builtin_amdgcn_global_load_lds(AS1(g), AS3(&Asm[buf][s << 3]), 16, 0, 0);
        }
        #pragma unroll
        for (int it = 0; it < 2; ++it) {
            const int s   = it * 256 + tid;
            const int row = s >> 3, c8 = s & 7;
            const unsigned short* g =
                WT + (size_t)(n0 + row) * K + k0 + ((c8 ^ (row & 7)) << 3);
            __builtin_amdgcn_global_load_lds(AS1(g), AS3(&Bsm[buf][s << 3]), 16, 0, 0);
        }
    };

    auto compute = [&](int buf) {
        #pragma unroll
        for (int kk = 0; kk < 2; ++kk) {
            short8 af[2], bf[2];
            const int cc = kk * 4 + hi;
            #pragma unroll
            for (int mf = 0; mf < 2; ++mf) {
                const int r = wm * 32 + mf * 16 + lnib;
                af[mf] = *(const short8*)&Asm[buf][(r * 8 + (cc ^ (r & 7))) << 3];
            }
            #pragma unroll
            for (int nf = 0; nf < 2; ++nf) {
                const int r = wn * 32 + nf * 16 + lnib;
                bf[nf] = *(const short8*)&Bsm[buf][(r * 8 + (cc ^ (r & 7))) << 3];
            }
            #pragma unroll
            for (int mf = 0; mf < 2; ++mf)
                #pragma unroll
                for (int nf = 0; nf < 2; ++nf)
                    acc[mf][nf] = __builtin_amdgcn_mfma_f32_16x16x32_bf16(
                        af[mf], bf[nf], acc[mf][nf], 0, 0, 0);
        }
    };

    constexpr int NT = K / BK;   // 24 K-steps

    stage(0, 0);
    __syncthreads();             // vmcnt(0) drain: buf0 ready

    int cur = 0;
    #pragma unroll 1
    for (int t = 0; t < NT - 1; ++t) {
        stage((t + 1) * BK, cur ^ 1);  // issue next tile's loads first
        compute(cur);                   // MFMA on current while loads fly
        __syncthreads();                // next buf ready; cur free to reuse
        cur ^= 1;
    }
    compute(cur);

    // Epilogue: bias + store. C/D: col = lane&15, row = hi*4 + reg.
    #pragma unroll
    for (int nf = 0; nf < 2; ++nf) {
        const int col = n0 + wn * 32 + nf * 16 + lnib;
        const float bv = bias[col];
        #pragma unroll
        for (int mf = 0; mf < 2; ++mf) {
            const int rbase = m0 + wm * 32 + mf * 16 + hi * 4;
            #pragma unroll
            for (int r = 0; r < 4; ++r)
                C[(size_t)(rbase + r) * N + col] = acc[mf][nf][r] + bv;
        }
    }
}

// ---------------------------------------------------------------------------
extern "C" void kernel_launch(void* const* d_in, const int* in_sizes, int n_in,
                              void* d_out, int out_size, void* d_ws, size_t ws_size,
                              hipStream_t stream)
{
    const float* repr  = (const float*)d_in[0];  // (B,L,D) f32
    const int*   spans = (const int*)  d_in[1];  // (B,S,2)
    const float* Wd    = (const float*)d_in[2];  // (2D,D) f32
    const float* bias  = (const float*)d_in[3];  // (D)    f32
    float* out = (float*)d_out;                  // (M, N) f32

    unsigned short* catb = (unsigned short*)d_ws;             // M*K = 12.6 MB
    unsigned short* WT   = catb + (size_t)M * K;              // N*K =  2.4 MB

    span_wt_kernel<<<4096 + 1152, 192, 0, stream>>>(repr, spans, Wd, catb, WT);
    gemm_bias_kernel<<<768, 256, 0, stream>>>(catb, WT, bias, out);
}